// Round 11
// baseline (36.532 us; speedup 1.0000x reference)
//
#include <hip/hip_runtime.h>
#include <math.h>

#define N_TOK 8192
#define DIM   4096
#define NEXP  8
#define TPW   4                 // tokens per wave-pair
#define HALF  (DIM / 2)         // each wave covers half of D
#define ITERS (HALF / 256)      // 8 iterations of 256 floats (lane*4)

typedef float f4 __attribute__((ext_vector_type(4)));   // native vec for nt loads

// EXACT R4 structure (best measured: 33.0 us) with ONE change:
// x loads are non-temporal (L1-allocation bypass probe for the ~4.8 TB/s
// read wall). w loads stay cached (L1/L2 reuse is real for w).
__global__ __launch_bounds__(256) void router_kernel(
    const float* __restrict__ x,   // [N_TOK, DIM]
    const float* __restrict__ w,   // [NEXP, DIM]
    float* __restrict__ out)       // [N_TOK*8] combine ++ [N_TOK*2] idx-as-float
{
    __shared__ float red[2][TPW][NEXP];

    const int lane   = threadIdx.x & 63;
    const int waveid = threadIdx.x >> 6;   // 0..3
    const int g      = waveid >> 1;        // token group within block
    const int h      = waveid & 1;         // d-half
    const int n0     = blockIdx.x * 8 + g * TPW;

    float acc[TPW][NEXP];
    #pragma unroll
    for (int t = 0; t < TPW; ++t)
        #pragma unroll
        for (int e = 0; e < NEXP; ++e) acc[t][e] = 0.0f;

    const int dbase = h * HALF + lane * 4;
    const float* xr = x + (size_t)n0 * DIM + dbase;  // token t at xr + t*DIM
    const float* wr = w + dbase;                     // expert e at wr + e*DIM

    // x prefetch: 3-slot rotation, issued 2 iterations ahead (R4 schedule).
    f4 xb[3][TPW];
    #pragma unroll
    for (int t = 0; t < TPW; ++t)
        xb[0][t] = __builtin_nontemporal_load((const f4*)(xr + (size_t)t * DIM));
    #pragma unroll
    for (int t = 0; t < TPW; ++t)
        xb[1][t] = __builtin_nontemporal_load((const f4*)(xr + (size_t)t * DIM + 256));

    #pragma unroll   // full unroll keeps %3 rotation statically indexed
    for (int it = 0; it < ITERS; ++it) {
        if (it + 2 < ITERS) {
            const int off = (it + 2) * 256;
            #pragma unroll
            for (int t = 0; t < TPW; ++t)
                xb[(it + 2) % 3][t] =
                    __builtin_nontemporal_load((const f4*)(xr + (size_t)t * DIM + off));
        }

        float4 wv[NEXP];   // cached loads (w reused across all blocks)
        #pragma unroll
        for (int e = 0; e < NEXP; ++e)
            wv[e] = *(const float4*)(wr + (size_t)e * DIM + it * 256);

        #pragma unroll
        for (int t = 0; t < TPW; ++t) {
            const f4 xv = xb[it % 3][t];
            #pragma unroll
            for (int e = 0; e < NEXP; ++e) {
                acc[t][e] = fmaf(xv.x, wv[e].x,
                            fmaf(xv.y, wv[e].y,
                            fmaf(xv.z, wv[e].z,
                            fmaf(xv.w, wv[e].w, acc[t][e]))));
            }
        }
    }

    // 64-lane butterfly: every lane ends with the half-D partial sum
    #pragma unroll
    for (int t = 0; t < TPW; ++t) {
        #pragma unroll
        for (int e = 0; e < NEXP; ++e) {
            float v = acc[t][e];
            #pragma unroll
            for (int off = 32; off >= 1; off >>= 1)
                v += __shfl_xor(v, off, 64);
            acc[t][e] = v;
        }
    }

    // half 1 -> LDS
    if (h == 1 && lane == 0) {
        #pragma unroll
        for (int t = 0; t < TPW; ++t) {
            *(float4*)&red[g][t][0] = make_float4(acc[t][0], acc[t][1], acc[t][2], acc[t][3]);
            *(float4*)&red[g][t][4] = make_float4(acc[t][4], acc[t][5], acc[t][6], acc[t][7]);
        }
    }
    __syncthreads();

    if (h == 0) {
        #pragma unroll
        for (int t = 0; t < TPW; ++t) {
            float4 r0 = *(const float4*)&red[g][t][0];   // broadcast reads
            float4 r1 = *(const float4*)&red[g][t][4];
            acc[t][0] += r0.x; acc[t][1] += r0.y; acc[t][2] += r0.z; acc[t][3] += r0.w;
            acc[t][4] += r1.x; acc[t][5] += r1.y; acc[t][6] += r1.z; acc[t][7] += r1.w;
        }

        #pragma unroll
        for (int t = 0; t < TPW; ++t) {
            // argmax: strict >, ascending scan => lowest index wins ties (lax.top_k)
            float m1 = acc[t][0]; int i1 = 0;
            #pragma unroll
            for (int e = 1; e < NEXP; ++e)
                if (acc[t][e] > m1) { m1 = acc[t][e]; i1 = e; }
            float m2 = -INFINITY; int i2 = 0;
            #pragma unroll
            for (int e = 0; e < NEXP; ++e)
                if (e != i1 && acc[t][e] > m2) { m2 = acc[t][e]; i2 = e; }

            // softmax denom cancels under top-2 renorm:
            // w1 = 1/(1+exp(l2-l1)), w2 = exp(l2-l1)/(1+exp(l2-l1))
            const float e2  = expf(m2 - m1);
            const float inv = 1.0f / (1.0f + e2);
            const float w1  = inv;
            const float w2  = e2 * inv;

            if (lane == 0) {
                const int n = n0 + t;
                float c[8];
                #pragma unroll
                for (int e = 0; e < 8; ++e)
                    c[e] = (e == i1) ? w1 : ((e == i2) ? w2 : 0.0f);
                float4* cp = (float4*)(out + (size_t)n * 8);
                cp[0] = make_float4(c[0], c[1], c[2], c[3]);
                cp[1] = make_float4(c[4], c[5], c[6], c[7]);
                float* ip = out + (size_t)N_TOK * 8 + (size_t)n * 2;
                ip[0] = (float)i1;
                ip[1] = (float)i2;
            }
        }
    }
}

extern "C" void kernel_launch(void* const* d_in, const int* in_sizes, int n_in,
                              void* d_out, int out_size, void* d_ws, size_t ws_size,
                              hipStream_t stream) {
    const float* x = (const float*)d_in[0];   // [8192, 4096] f32
    const float* w = (const float*)d_in[1];   // [8, 4096] f32
    float* out = (float*)d_out;

    dim3 grid(N_TOK / 8);   // 1024 blocks x 8 tokens
    dim3 block(256);
    hipLaunchKernelGGL(router_kernel, grid, block, 0, stream, x, w, out);
}